// Round 12
// baseline (64.592 us; speedup 1.0000x reference)
//
#include <hip/hip_runtime.h>
#include <hip/hip_bf16.h>

typedef __attribute__((ext_vector_type(8))) short bf16x8;
typedef __attribute__((ext_vector_type(4))) float f32x4;

#define MFMA16(A,B,C) __builtin_amdgcn_mfma_f32_16x16x32_bf16((A),(B),(C),0,0,0)

static __device__ __forceinline__ f32x4 ld4(const float* p){
  return *(const f32x4*)p;
}
// Single-instruction packed f32->bf16 (RTNE).
static __device__ __forceinline__ unsigned pk2(float a, float b){
  unsigned r;
  asm("v_cvt_pk_bf16_f32 %0, %1, %2" : "=v"(r) : "v"(a), "v"(b));
  return r;
}
static __device__ __forceinline__ bf16x8 mk8(float a,float b,float c,float d,
                                             float e,float f,float g,float h){
  union { bf16x8 v; unsigned u[4]; } r;
  r.u[0]=pk2(a,b); r.u[1]=pk2(c,d); r.u[2]=pk2(e,f); r.u[3]=pk2(g,h);
  return r.v;
}
static __device__ __forceinline__ bf16x8 mk8v(f32x4 a, f32x4 b){
  return mk8(a[0],a[1],a[2],a[3],b[0],b[1],b[2],b[3]);
}
static __device__ __forceinline__ bf16x8 mk8r(f32x4 a, f32x4 b){ // relu + pack
  return mk8(fmaxf(a[0],0.f),fmaxf(a[1],0.f),fmaxf(a[2],0.f),fmaxf(a[3],0.f),
             fmaxf(b[0],0.f),fmaxf(b[1],0.f),fmaxf(b[2],0.f),fmaxf(b[3],0.f));
}
static __device__ __forceinline__ bf16x8 zero8(){
  bf16x8 v;
  #pragma unroll
  for(int i=0;i<8;++i) v[i]=0;
  return v;
}
static __device__ __forceinline__ bf16x8 one8(){   // [1.0, 0, ..., 0] in bf16
  bf16x8 v = zero8();
  v[0] = (short)0x3F80;
  return v;
}
// Pins: weights ride the AGPR file (builtin MFMA reads them via AV class,
// verified VALU-lean in R7); zero4/z0f stay VGPR.
static __device__ __forceinline__ void keepa(bf16x8& v){ asm("" : "+a"(v)); }
static __device__ __forceinline__ void keepaf(f32x4& v){ asm("" : "+a"(v)); }
static __device__ __forceinline__ void keepv(bf16x8& v){ asm("" : "+v"(v)); }
static __device__ __forceinline__ void keepvf(f32x4& v){ asm("" : "+v"(v)); }

// Layout conventions (verified C/D layout, learn_hip m89):
//   A-frag: row = lane&15, k = (lane>>4)*8 + j          (weights)
//   B-frag: col = lane&15, k = (lane>>4)*8 + j          (batch activations)
//   C/D   : col = lane&15, row = (lane>>4)*4 + reg
// Scramble sigma: feature h = Mt*16 + hi*4 + reg  <->  k-slot Kt*32 + hi*8 + jj
//   (Kt = Mt>>1, jj = (Mt&1)*4 + reg) applied to Wt2/Wh2 K-cols, z-cols of
//   Wt1/Wh1, and z0, so layer-out feeds layer-in with no cross-lane moves.
//
// R12 bias restructure (occupancy lever; R7 was ~264 unified regs -> 1.5
// waves/SIMD, no cross-wave MFMA/VALU overlap):
//  - y K-tile slot k=16 carries a constant 1.0 in yf; weight fragments carry
//    bt1' (tiny L1) / bh1' (head L1) in that column -> bias regs gone.
//  - bt2 folded forward: z flows bias-free (zhat); bt1' = bt1 + Wt1_z@bt2,
//    bh1' = bh1 + Wh1_z@bt2, z0f packs (z0 - bt2). Exact algebra.
//  - accumulators init from a single pinned zero4; only bh2r stays resident.
__global__ __launch_bounds__(256, 2) void trm_mfma(
    const float* __restrict__ state, const int* __restrict__ pact,
    const float* __restrict__ z0,
    const float* __restrict__ Wt1, const float* __restrict__ bt1,
    const float* __restrict__ Wt2, const float* __restrict__ bt2,
    const float* __restrict__ Wh1, const float* __restrict__ bh1,
    const float* __restrict__ Wh2, const float* __restrict__ bh2,
    const float* __restrict__ emb, float* __restrict__ out,
    int ntiles, int wstride)
{
  __shared__ __align__(16) float ef[64];          // emb 4x16 staged once
  const int lane = threadIdx.x & 63;
  const int wid  = blockIdx.x * (blockDim.x >> 6) + (threadIdx.x >> 6);
  const int r16  = lane & 15;   // A-row / B-col / C-col
  const int hi   = lane >> 4;   // k-group (inputs) / row-group (C)
  const int he   = hi & 1;

  if (threadIdx.x < 64) ef[threadIdx.x] = emb[threadIdx.x];
  __syncthreads();

  // ---- bt2 vector (feature-indexed) + folded-bias dots (prologue only) ----
  f32x4 b2[8];
  #pragma unroll
  for (int q=0;q<8;++q) b2[q] = ld4(bt2 + q*4);
  float bt1p[4];
  #pragma unroll
  for (int m=0;m<4;++m){
    const float* w = Wt1 + (m*16 + r16)*112;
    f32x4 s = b2[0]*ld4(w);
    #pragma unroll
    for (int q=1;q<8;++q) s += b2[q]*ld4(w + q*4);
    bt1p[m] = bt1[m*16 + r16] + s[0]+s[1]+s[2]+s[3];
  }
  float bh1p[2];
  #pragma unroll
  for (int m=0;m<2;++m){
    const float* w = Wh1 + (m*16 + r16)*48;
    f32x4 s = b2[0]*ld4(w);
    #pragma unroll
    for (int q=1;q<8;++q) s += b2[q]*ld4(w + q*4);
    bh1p[m] = bh1[m*16 + r16] + s[0]+s[1]+s[2]+s[3];
  }

  // ------------- weights: persistent, pinned into the AGPR file ------------
  bf16x8 wt1f[4][4];
  #pragma unroll
  for (int m=0;m<4;++m){
    const float* w = Wt1 + (m*16 + r16)*112;
    wt1f[m][0] = mk8v(ld4(w + hi*4),       ld4(w + 16 + hi*4));   // z (scrambled)
    wt1f[m][1] = mk8v(ld4(w + 32 + hi*8),  ld4(w + 36 + hi*8));   // x[0:32]
    wt1f[m][2] = mk8v(ld4(w + 64 + hi*8),  ld4(w + 68 + hi*8));   // x[32:64]
    bf16x8 yfrag;                                                 // y | bias | 0
    if (hi < 2)       yfrag = mk8v(ld4(w + 96 + hi*8), ld4(w + 100 + hi*8));
    else if (hi == 2) yfrag = mk8(bt1p[m],0.f,0.f,0.f,0.f,0.f,0.f,0.f);
    else              yfrag = zero8();
    wt1f[m][3] = yfrag;
    keepa(wt1f[m][0]); keepa(wt1f[m][1]); keepa(wt1f[m][2]); keepa(wt1f[m][3]);
  }
  bf16x8 wt2f[2][2];
  #pragma unroll
  for (int m=0;m<2;++m){
    const float* w = Wt2 + (m*16 + r16)*64;
    wt2f[m][0] = mk8v(ld4(w + hi*4),      ld4(w + 16 + hi*4));    // h-cols scrambled
    wt2f[m][1] = mk8v(ld4(w + 32 + hi*4), ld4(w + 48 + hi*4));
    keepa(wt2f[m][0]); keepa(wt2f[m][1]);
  }
  bf16x8 wh1f[2][2];
  #pragma unroll
  for (int m=0;m<2;++m){
    const float* w = Wh1 + (m*16 + r16)*48;
    wh1f[m][0] = mk8v(ld4(w + hi*4), ld4(w + 16 + hi*4));         // z (scrambled)
    bf16x8 yfrag;                                                 // y | bias | 0
    if (hi < 2)       yfrag = mk8v(ld4(w + 32 + hi*8), ld4(w + 36 + hi*8));
    else if (hi == 2) yfrag = mk8(bh1p[m],0.f,0.f,0.f,0.f,0.f,0.f,0.f);
    else              yfrag = zero8();
    wh1f[m][1] = yfrag;
    keepa(wh1f[m][0]); keepa(wh1f[m][1]);
  }
  bf16x8 wh2f;
  {
    const float* w = Wh2 + ((r16 < 4) ? r16 : 0)*32;
    bf16x8 t = mk8v(ld4(w + hi*4), ld4(w + 16 + hi*4));           // h-cols scrambled
    if (r16 >= 4) t = zero8();                                    // pad rows 4..15
    wh2f = t;
    keepa(wh2f);
  }
  f32x4 bh2r;                                   // head L2 bias (C-init), AGPR
  {
    f32x4 t = ld4(bh2);
    float msk = (hi == 0) ? 1.f : 0.f;
    bh2r = t * msk;
    keepaf(bh2r);
  }
  f32x4 zero4 = {0.f, 0.f, 0.f, 0.f};           // shared C-init
  keepvf(zero4);
  bf16x8 z0f;                                   // (z0 - bt2), scrambled
  {
    f32x4 za = ld4(z0 + hi*4)      - ld4(bt2 + hi*4);
    f32x4 zb = ld4(z0 + 16 + hi*4) - ld4(bt2 + 16 + hi*4);
    z0f = mk8v(za, zb);
    keepv(z0f);
  }

  // ---------------- batch-tile loop (16 cols per wave-iteration) -----------
  int t = wid;
  f32x4 cx0, cx1, cx2, cx3; int cact;
  {
    const int col = t*16 + r16;
    const float* xr = state + (size_t)col*64;
    cx0 = ld4(xr + hi*8);      cx1 = ld4(xr + hi*8 + 4);
    cx2 = ld4(xr + 32 + hi*8); cx3 = ld4(xr + 36 + hi*8);
    cact = pact[col];
  }

  #pragma unroll 1
  for (; t < ntiles; t += wstride){
    const int col = t*16 + r16;
    bf16x8 xf0 = mk8v(cx0, cx1);
    bf16x8 xf1 = mk8v(cx2, cx3);
    bf16x8 yf;
    {
      const float* er = ef + cact*16 + he*8;    // LDS broadcast
      yf = mk8v(ld4(er), ld4(er + 4));
      if (hi == 2) yf = one8();                 // k=16 -> 1.0 (bias slot)
      if (hi == 3) yf = zero8();
    }

    // prefetch next tile's state/action (hides under the MFMA body)
    const int tn = t + wstride;
    if (tn < ntiles){
      const int coln = tn*16 + r16;
      const float* xrn = state + (size_t)coln*64;
      cx0 = ld4(xrn + hi*8);      cx1 = ld4(xrn + hi*8 + 4);
      cx2 = ld4(xrn + 32 + hi*8); cx3 = ld4(xrn + 36 + hi*8);
      cact = pact[coln];
    }

    bf16x8 zf = z0f;
    f32x4 lgv;

    #pragma unroll
    for (int s=0;s<2;++s){
      #pragma unroll
      for (int itr=0; itr<2; ++itr){
        f32x4 c0 = MFMA16(wt1f[0][0], zf, zero4);
        f32x4 c1 = MFMA16(wt1f[1][0], zf, zero4);
        f32x4 c2 = MFMA16(wt1f[2][0], zf, zero4);
        f32x4 c3 = MFMA16(wt1f[3][0], zf, zero4);
        c0=MFMA16(wt1f[0][1], xf0, c0); c1=MFMA16(wt1f[1][1], xf0, c1);
        c2=MFMA16(wt1f[2][1], xf0, c2); c3=MFMA16(wt1f[3][1], xf0, c3);
        c0=MFMA16(wt1f[0][2], xf1, c0); c1=MFMA16(wt1f[1][2], xf1, c1);
        c2=MFMA16(wt1f[2][2], xf1, c2); c3=MFMA16(wt1f[3][2], xf1, c3);
        c0=MFMA16(wt1f[0][3], yf,  c0); c1=MFMA16(wt1f[1][3], yf,  c1);
        c2=MFMA16(wt1f[2][3], yf,  c2); c3=MFMA16(wt1f[3][3], yf,  c3);
        bf16x8 h0 = mk8r(c0, c1);             // K-tile 0 of hidden (scrambled)
        bf16x8 h1 = mk8r(c2, c3);             // K-tile 1
        f32x4 d0 = MFMA16(wt2f[0][0], h0, zero4);
        f32x4 d1 = MFMA16(wt2f[1][0], h0, zero4);
        d0=MFMA16(wt2f[0][1], h1, d0);
        d1=MFMA16(wt2f[1][1], h1, d1);
        zf = mk8v(d0, d1);                    // zhat (bias-free), in-lane
      }
      f32x4 g0 = MFMA16(wh1f[0][0], zf, zero4);
      f32x4 g1 = MFMA16(wh1f[1][0], zf, zero4);
      g0=MFMA16(wh1f[0][1], yf, g0);
      g1=MFMA16(wh1f[1][1], yf, g1);
      bf16x8 hh = mk8r(g0, g1);
      f32x4 cl = MFMA16(wh2f, hh, bh2r);      // logits: hi==0 lanes, regs 0..3
      lgv = cl;
      if (s == 0){
        float l0 = __shfl(cl[0], r16), l1 = __shfl(cl[1], r16);
        float l2 = __shfl(cl[2], r16), l3 = __shfl(cl[3], r16);
        float mx = fmaxf(fmaxf(l0,l1), fmaxf(l2,l3));
        float p0=__expf(l0-mx), p1=__expf(l1-mx);
        float p2=__expf(l2-mx), p3=__expf(l3-mx);
        float inv = 1.f/(p0+p1+p2+p3);
        p0*=inv; p1*=inv; p2*=inv; p3*=inv;
        const float* eb = ef + he*8;          // LDS
        f32x4 ya = ld4(eb)*p0      + ld4(eb+16)*p1 +
                   ld4(eb+32)*p2   + ld4(eb+48)*p3;
        f32x4 yb = ld4(eb+4)*p0    + ld4(eb+20)*p1 +
                   ld4(eb+36)*p2   + ld4(eb+52)*p3;
        yf = mk8v(ya, yb);
        if (hi == 2) yf = one8();
        if (hi == 3) yf = zero8();
      }
    }
    if (hi == 0) *(f32x4*)(out + (size_t)col*4) = lgv;
  }
}

extern "C" void kernel_launch(void* const* d_in, const int* in_sizes, int n_in,
                              void* d_out, int out_size, void* d_ws, size_t ws_size,
                              hipStream_t stream) {
  const float* state = (const float*)d_in[0];
  const int*   pact  = (const int*)  d_in[1];
  const float* z0    = (const float*)d_in[2];
  const float* Wt1   = (const float*)d_in[3];
  const float* bt1   = (const float*)d_in[4];
  const float* Wt2   = (const float*)d_in[5];
  const float* bt2   = (const float*)d_in[6];
  const float* Wh1   = (const float*)d_in[7];
  const float* bh1   = (const float*)d_in[8];
  const float* Wh2   = (const float*)d_in[9];
  const float* bh2   = (const float*)d_in[10];
  const float* emb   = (const float*)d_in[11];
  float* out = (float*)d_out;

  const int B = in_sizes[0] / 64;         // 524288
  const int ntiles = B / 16;              // 32768 16-col tiles
  const int blocks = 512;                 // 2 blocks/CU, 4 waves each
  const int wstride = blocks * 4;         // 2048 waves -> 16 tiles/wave
  trm_mfma<<<blocks, 256, 0, stream>>>(state, pact, z0, Wt1, bt1, Wt2, bt2,
                                       Wh1, bh1, Wh2, bh2, emb, out,
                                       ntiles, wstride);
}